// Round 1
// baseline (166.968 us; speedup 1.0000x reference)
//
#include <hip/hip_runtime.h>
#include <math.h>

// CapsuleLayer: u = x@W via split-precision f16 MFMA (xh@Wh + xl@Wh + xh@Wl),
// 32x32x16. R11: attack B-operand latency (R10 counters: MfmaUtil 25% ==
// 48-cyc issue window / ~load-latency; everything latency-bound):
//  - Ring-4 B prefetch (slot = nt, distance = 4 nt-steps = 1 kt): window
//    grows 48 -> ~150-200 cyc. +16 VGPR (fits: 232 -> ~248 <= 256, 2 w/SIMD).
//  - Non-temporal x loads / out stores: x (64 MB/dispatch, zero reuse) was
//    streaming through per-XCD L2 (8 MB thru 4 MB) and evicting W -> B loads
//    fell to L3 (~500cy). nt flag keeps W L2-resident (~200cy).
//  - Wh/Wl interleaved into one Whl array: per-lane bh/bl pair in ONE 64B
//    line (half the L2 transactions, single base address).
// Proven invariants kept byte-identical: A staging swizzle + frag reads,
// never runtime-index acc[] (R6 spill), lane-bit-5 cross only via bpermute
// (R5), C/D layout row=(reg&3)+8*(reg>>2)+4*q col=ln, epilogue routing.
//
// x: [32768,512] fp32  W: [512,512] fp32  v: [32768,32] fp32
// prep_w: W[k][n] -> Whl tiled [kt][n][{h,l}][k%16] f16 in d_ws (1 MB).
// Main: block = 256 thr (4 waves), tile 64 rows x 512 cols, grid 512
// (2 blocks/CU: LDS 66.56KB, VGPR+AGPR<=256 via __launch_bounds__(256,2)).
// Wave w: all 64 rows (2 m-frags) x cols w*128..+127 (4 n-tiles).

#define BATCH   32768
#define KDIM    512
#define NDIM    512
#define OUT_DIM 32
#define EPS_F   1e-8f
#define NKT     32            // K tiles of 16
#define KPS     8             // kt per superblock
#define NSB     4             // superblocks

typedef _Float16 half8  __attribute__((ext_vector_type(8)));
typedef _Float16 half4t __attribute__((ext_vector_type(4)));
typedef float   floatx4 __attribute__((ext_vector_type(4)));
typedef float  floatx16 __attribute__((ext_vector_type(16)));

// ---- cross-lane helpers (R7, proven) ----
template <int CTRL>
__device__ __forceinline__ float dpp_mov(float x) {
    return __int_as_float(__builtin_amdgcn_mov_dpp(__float_as_int(x), CTRL, 0xF, 0xF, true));
}
template <int XMASK>   // XMASK <= 31: ds_swizzle BitMode xor (within 32-lane group)
__device__ __forceinline__ float swz_xor(float x) {
    return __int_as_float(__builtin_amdgcn_ds_swizzle(__float_as_int(x), (XMASK << 10) | 31));
}
#define ROR4  0x124
#define ROR8  0x128
#define QXOR1 0xB1
#define QXOR2 0x4E

__device__ __forceinline__ float cap_sum(float x) {
    x += dpp_mov<ROR4>(x);
    x += dpp_mov<ROR8>(x);
    x += swz_xor<16>(x);
    x += __shfl_xor(x, 32);          // lane bit 5: bpermute only
    return x;
}
__device__ __forceinline__ float cap_max(float x) {
    x = fmaxf(x, dpp_mov<ROR4>(x));
    x = fmaxf(x, dpp_mov<ROR8>(x));
    x = fmaxf(x, swz_xor<16>(x));
    x = fmaxf(x, __shfl_xor(x, 32));
    return x;
}
__device__ __forceinline__ float dg_sum(float x) {
    x += dpp_mov<QXOR1>(x);
    x += dpp_mov<QXOR2>(x);
    return x;
}

// ---- prep: W[k][n] fp32 -> Whl [kt][n][{h(16B),l(16B)} per q] f16 ----
// Layout in halfs: off = kt*16384 + n*32 + (k&15); h at off, l at off+16.
// => per column n: 64 B = {h_q0(8h), h_q1(8h), l_q0(8h), l_q1(8h)}.
__global__ void prep_w(const float* __restrict__ W, _Float16* __restrict__ Whl) {
    __shared__ float tile[32][33];
    const int tx = threadIdx.x, ty = threadIdx.y;      // block (32, 8)
    const int n0 = blockIdx.x * 32, k0 = blockIdx.y * 32;
#pragma unroll
    for (int i = 0; i < 4; ++i)
        tile[ty + 8 * i][tx] = W[(size_t)(k0 + ty + 8 * i) * NDIM + n0 + tx];
    __syncthreads();
#pragma unroll
    for (int i = 0; i < 4; ++i) {
        const int k = k0 + tx, n = n0 + ty + 8 * i;
        const float v = tile[tx][ty + 8 * i];          // = W[k][n]
        const _Float16 h = (_Float16)v;
        const _Float16 l = (_Float16)(v - (float)h);
        const size_t off = (size_t)(k >> 4) * (NDIM * 32) + (size_t)n * 32 + (k & 15);
        Whl[off]      = h;
        Whl[off + 16] = l;
    }
}

__global__ __launch_bounds__(256, 2)
void capsule_mfma(const float* __restrict__ x, const _Float16* __restrict__ Whl,
                  float* __restrict__ out) {
    // As[buf(2)][kt'(8)][row 64][64B] = 64 KB, unioned with u_lds[32][520] (66.56 KB)
    __shared__ __align__(16) char smem[66560];
    float (*u_lds)[520] = (float (*)[520])smem;

    const int tid  = threadIdx.x;
    const int w    = tid >> 6;          // wave 0..3
    const int lane = tid & 63;
    const int ln = lane & 31, q = lane >> 5;
    const int rowBlk = blockIdx.x * 64;
    const int C0 = w * 128;

    floatx16 acc[2][4];
#pragma unroll
    for (int mf = 0; mf < 2; ++mf)
#pragma unroll
        for (int nt = 0; nt < 4; ++nt)
#pragma unroll
            for (int i = 0; i < 16; ++i) acc[mf][nt][i] = 0.f;

    // ---- A staging mapping: thread -> (row srow0+8i, kt' skt, quarter skq) ----
    const int srow0 = tid >> 5;          // 0..7
    const int sf    = tid & 31;
    const int skt   = sf >> 2;           // 0..7
    const int skq   = sf & 3;
    const float* aga = x + (size_t)(rowBlk + srow0) * KDIM + skt * 16 + skq * 4;
    const int ssw = (srow0 >> 1) & 3;    // i-invariant ((+8i)>>1 adds 4, &3 unchanged)
    const int woffh = skt * 4096 + srow0 * 64 + (((skq >> 1) ^ ssw) * 16) + (skq & 1) * 8;
    // l-chunk offset = woffh ^ 32

    // ---- A frag read offsets: hoff1 = hoff0 + 2048; loff = hoff^32
    const int hoff0 = ln * 64 + ((q ^ ((ln >> 1) & 3)) * 16);

    // ---- B lane offset (halfs) within a (kt,nt) block of interleaved Whl ----
    // col = C0 + nt*32 + ln; h chunk at col*32 + q*8, l at +16.
    const int lane_off = (C0 + ln) * 32 + q * 8;   // + nt*1024 + kt*16384

    // ---- prologue: B ring for kt=0; stage slice 0 -> buf0 ----
    half8 bh[4], bl[4];
#pragma unroll
    for (int nt = 0; nt < 4; ++nt) {
        const _Float16* bp = Whl + nt * 1024 + lane_off;
        bh[nt] = *(const half8*)bp;
        bl[nt] = *(const half8*)(bp + 16);
    }
    {
        floatx4 s0[8];
#pragma unroll
        for (int i = 0; i < 8; ++i)
            s0[i] = __builtin_nontemporal_load((const floatx4*)(aga + (size_t)(8 * i) * KDIM));
#pragma unroll
        for (int i = 0; i < 8; ++i) {
            half4t h4, l4;
#pragma unroll
            for (int j = 0; j < 4; ++j) {
                h4[j] = (_Float16)s0[i][j];
                l4[j] = (_Float16)(s0[i][j] - (float)h4[j]);
            }
            *(half4t*)(smem + woffh + i * 512)        = h4;
            *(half4t*)(smem + (woffh ^ 32) + i * 512) = l4;
        }
    }

    // Per nt-step: consume bh/bl[nt] (6 MFMA), then prefetch (kt+1, nt) into
    // the same slot -> distance 4 steps, loads never drained inside the sb.
#define COMPUTE_KK(kk)                                                          \
    {                                                                           \
        const int kt = s * KPS + (kk);                                          \
        const char* ab = smem + abuf + (kk) * 4096;                             \
        const half8 ah0 = *(const half8*)(ab + hoff0);                          \
        const half8 al0 = *(const half8*)(ab + (hoff0 ^ 32));                   \
        const half8 ah1 = *(const half8*)(ab + hoff0 + 2048);                   \
        const half8 al1 = *(const half8*)(ab + ((hoff0 + 2048) ^ 32));          \
        const int ktn = (kt + 1 < NKT) ? kt + 1 : kt;                           \
        const _Float16* bkt = Whl + (size_t)ktn * 16384 + lane_off;             \
        _Pragma("unroll")                                                       \
        for (int nt = 0; nt < 4; ++nt) {                                        \
            acc[0][nt] = __builtin_amdgcn_mfma_f32_32x32x16_f16(ah0, bh[nt], acc[0][nt], 0, 0, 0); \
            acc[0][nt] = __builtin_amdgcn_mfma_f32_32x32x16_f16(al0, bh[nt], acc[0][nt], 0, 0, 0); \
            acc[1][nt] = __builtin_amdgcn_mfma_f32_32x32x16_f16(ah1, bh[nt], acc[1][nt], 0, 0, 0); \
            acc[1][nt] = __builtin_amdgcn_mfma_f32_32x32x16_f16(al1, bh[nt], acc[1][nt], 0, 0, 0); \
            acc[0][nt] = __builtin_amdgcn_mfma_f32_32x32x16_f16(ah0, bl[nt], acc[0][nt], 0, 0, 0); \
            acc[1][nt] = __builtin_amdgcn_mfma_f32_32x32x16_f16(ah1, bl[nt], acc[1][nt], 0, 0, 0); \
            bh[nt] = *(const half8*)(bkt + nt * 1024);                          \
            bl[nt] = *(const half8*)(bkt + nt * 1024 + 16);                     \
        }                                                                       \
    }

#define STAGE_HALF(h0)                                                          \
    {                                                                           \
        half4t h4, l4;                                                          \
        _Pragma("unroll")                                                       \
        for (int i = 0; i < 4; ++i) {                                           \
            _Pragma("unroll")                                                   \
            for (int j = 0; j < 4; ++j) {                                       \
                h4[j] = (_Float16)sv[i][j];                                     \
                l4[j] = (_Float16)(sv[i][j] - (float)h4[j]);                    \
            }                                                                   \
            *(half4t*)(smem + nbuf + woffh + ((h0) + i) * 512)        = h4;     \
            *(half4t*)(smem + nbuf + ((woffh ^ 32)) + ((h0) + i) * 512) = l4;   \
        }                                                                       \
    }

#pragma unroll 1
    for (int s = 0; s < NSB; ++s) {
        __syncthreads();               // stage(slice s) visible; buf^1 readers done
        const int abuf = (s & 1) * 32768;
        const int nbuf = abuf ^ 32768;
        floatx4 sv[4];
        if (s + 1 < NSB) {             // load half 0 of slice s+1 (rows +0..+24)
#pragma unroll
            for (int i = 0; i < 4; ++i)
                sv[i] = __builtin_nontemporal_load(
                    (const floatx4*)(aga + (size_t)(s + 1) * 128 + (size_t)(8 * i) * KDIM));
        }
        COMPUTE_KK(0)
        COMPUTE_KK(1)
        if (s + 1 < NSB) STAGE_HALF(0)
        if (s + 1 < NSB) {             // load half 1 (rows +32..+56)
#pragma unroll
            for (int i = 0; i < 4; ++i)
                sv[i] = __builtin_nontemporal_load(
                    (const floatx4*)(aga + (size_t)(s + 1) * 128 + (size_t)(8 * (i + 4)) * KDIM));
        }
        COMPUTE_KK(2)
        COMPUTE_KK(3)
        COMPUTE_KK(4)
        COMPUTE_KK(5)
        if (s + 1 < NSB) STAGE_HALF(4)
        COMPUTE_KK(6)
        COMPUTE_KK(7)
    }

    // ---- epilogue: two 32-row phases; acc -> u_lds fp32, then routing ----
    // C/D layout 32x32: col = ln, row = (reg&3) + 8*(reg>>2) + 4*q
    const int dgrp = lane & 3;
#pragma unroll
    for (int p = 0; p < 2; ++p) {
        __syncthreads();               // K-loop / previous-phase LDS reads done
        {
            const int mf = p;          // compile-time (p unrolled) — R6 rule
#pragma unroll
            for (int nt = 0; nt < 4; ++nt)
#pragma unroll
                for (int reg = 0; reg < 16; ++reg)
                    u_lds[(reg & 3) + 8 * (reg >> 2) + 4 * q][C0 + nt * 32 + ln] = acc[mf][nt][reg];
        }
        __syncthreads();
#pragma unroll 1
        for (int ri = 0; ri < 8; ++ri) {
            const int rl = w * 8 + ri;               // local row 0..31
            const floatx4 ua = *(const floatx4*)&u_lds[rl][lane * 8];
            const floatx4 ub = *(const floatx4*)&u_lds[rl][lane * 8 + 4];
            const float u8[8] = {ua[0], ua[1], ua[2], ua[3],
                                 ub[0], ub[1], ub[2], ub[3]};
            float b_own = 0.f;
            float v[8];
#pragma unroll
            for (int it = 0; it < 3; ++it) {
                float c_own;
                if (it == 0) {
                    c_own = 1.0f / 16.0f;            // softmax of zeros
                } else {
                    const float m = cap_max(b_own);
                    const float e = __expf(b_own - m);
                    const float ssum = cap_sum(e);
                    c_own = e / ssum;
                }
                float s8[8];
#pragma unroll
                for (int j = 0; j < 8; ++j) s8[j] = c_own * u8[j];
#pragma unroll
                for (int j = 0; j < 8; ++j) s8[j] += dpp_mov<ROR4>(s8[j]);
#pragma unroll
                for (int j = 0; j < 8; ++j) s8[j] += dpp_mov<ROR8>(s8[j]);
#pragma unroll
                for (int j = 0; j < 8; ++j) s8[j] += swz_xor<16>(s8[j]);
#pragma unroll
                for (int j = 0; j < 8; ++j) s8[j] += __shfl_xor(s8[j], 32);
                float nrm = 0.f;
#pragma unroll
                for (int j = 0; j < 8; ++j) nrm = fmaf(s8[j], s8[j], nrm);
                nrm = dg_sum(nrm);
                const float scale = nrm / ((1.f + nrm) * (sqrtf(nrm) + EPS_F));
#pragma unroll
                for (int j = 0; j < 8; ++j) v[j] = scale * s8[j];
                if (it < 2) {
                    float dot = 0.f;
#pragma unroll
                    for (int j = 0; j < 8; ++j) dot = fmaf(u8[j], v[j], dot);
                    dot = dg_sum(dot);
                    b_own += dot;
                }
            }
            if (lane < 4) {
                float* o = out + (size_t)(rowBlk + p * 32 + rl) * OUT_DIM + dgrp * 8;
                floatx4 o0 = {v[0], v[1], v[2], v[3]};
                floatx4 o1 = {v[4], v[5], v[6], v[7]};
                __builtin_nontemporal_store(o0, (floatx4*)o);
                __builtin_nontemporal_store(o1, (floatx4*)(o + 4));
            }
        }
    }
}

extern "C" void kernel_launch(void* const* d_in, const int* in_sizes, int n_in,
                              void* d_out, int out_size, void* d_ws, size_t ws_size,
                              hipStream_t stream) {
    const float* x = (const float*)d_in[0];   // [32768, 512]
    const float* W = (const float*)d_in[1];   // [512, 512]
    float* out = (float*)d_out;               // [32768, 32]
    _Float16* Whl = (_Float16*)d_ws;          // [32][512][2][16] f16 tiled, 1 MB

    prep_w<<<dim3(16, 16), dim3(32, 8), 0, stream>>>(W, Whl);
    capsule_mfma<<<dim3(BATCH / 64), dim3(256), 0, stream>>>(x, Whl, out);
}